// Round 11
// baseline (623.821 us; speedup 1.0000x reference)
//
#include <hip/hip_runtime.h>
#include <math.h>

#define B_     256
#define S_     500
#define QD_    128
#define M_     64
#define VD_    256
#define NQ_    10000          // q indices in [0, 10000]
#define NQA_   20000          // qa indices in [0, 20000]
#define WROWS  (NQ_ + 1)
#define EAROWS (NQA_ + 1)

// quad-local reduction adds via DPP (pure VALU): x += x[lane^1]; x += x[lane^2]
__device__ __forceinline__ float qadd1(float x)
{
    int r = __builtin_amdgcn_mov_dpp(__float_as_int(x), 0xB1, 0xF, 0xF, true);
    return x + __int_as_float(r);
}
__device__ __forceinline__ float qadd2(float x)
{
    int r = __builtin_amdgcn_mov_dpp(__float_as_int(x), 0x4E, 0xF, 0xF, true);
    return x + __int_as_float(r);
}

// ---------------------------------------------------------------------------
// Transpose key_mem [64][128] into quad layout kTq[k4*64 + m].
// ---------------------------------------------------------------------------
__global__ void kT_kernel(const float* __restrict__ key_mem, float4* __restrict__ kTq)
{
    int i = blockIdx.x * 256 + threadIdx.x;
    if (i < 32 * 64) {
        int m  = i & 63;
        int k4 = i >> 6;
        kTq[i] = *reinterpret_cast<const float4*>(&key_mem[m * QD_ + k4 * 4]);
    }
}

// ---------------------------------------------------------------------------
// wtab[r][m] = softmax_m( q_embed_w[r] . key_mem[m] ),  r in [0, WROWS)
// ---------------------------------------------------------------------------
__global__ __launch_bounds__(256) void wtab_kernel(
    const float*  __restrict__ q_embed_w,
    const float4* __restrict__ kTq,
    float*        __restrict__ wtab)
{
    __shared__ float4 q4[16][32];

    const int tid = threadIdx.x;
    const int r0  = blockIdx.x * 16;

    for (int i = tid; i < 512; i += 256) {
        int row = i >> 5, k4 = i & 31;
        int r   = r0 + row; if (r > NQ_) r = NQ_;
        q4[row][k4] = *reinterpret_cast<const float4*>(
            &q_embed_w[(size_t)r * QD_ + k4 * 4]);
    }
    __syncthreads();

    const int wave = tid >> 6, lane = tid & 63;
    const int rr = wave * 4;

    float s0 = 0.f, s1 = 0.f, s2 = 0.f, s3 = 0.f;
    for (int k4 = 0; k4 < 32; ++k4) {
        float4 kv = kTq[k4 * 64 + lane];
        float4 a0 = q4[rr + 0][k4];
        float4 a1 = q4[rr + 1][k4];
        float4 a2 = q4[rr + 2][k4];
        float4 a3 = q4[rr + 3][k4];
        s0 = fmaf(a0.x, kv.x, s0); s0 = fmaf(a0.y, kv.y, s0);
        s0 = fmaf(a0.z, kv.z, s0); s0 = fmaf(a0.w, kv.w, s0);
        s1 = fmaf(a1.x, kv.x, s1); s1 = fmaf(a1.y, kv.y, s1);
        s1 = fmaf(a1.z, kv.z, s1); s1 = fmaf(a1.w, kv.w, s1);
        s2 = fmaf(a2.x, kv.x, s2); s2 = fmaf(a2.y, kv.y, s2);
        s2 = fmaf(a2.z, kv.z, s2); s2 = fmaf(a2.w, kv.w, s2);
        s3 = fmaf(a3.x, kv.x, s3); s3 = fmaf(a3.y, kv.y, s3);
        s3 = fmaf(a3.z, kv.z, s3); s3 = fmaf(a3.w, kv.w, s3);
    }

    float s[4] = { s0, s1, s2, s3 };
    #pragma unroll
    for (int j = 0; j < 4; ++j) {
        float mx = s[j];
        #pragma unroll
        for (int off = 32; off; off >>= 1) mx = fmaxf(mx, __shfl_xor(mx, off));
        float e = __expf(s[j] - mx);
        float sum = e;
        #pragma unroll
        for (int off = 32; off; off >>= 1) sum += __shfl_xor(sum, off);
        if (r0 + rr + j < WROWS)
            wtab[(size_t)(r0 + rr + j) * 64 + lane] = e / sum;
    }
}

// ---------------------------------------------------------------------------
// eatab INTERLEAVED: eatab[r][c*2+0] = sigmoid(...), [c*2+1] = tanh(...)
// so the scan fetches (e,a) for a column in ONE dwordx2.
// ---------------------------------------------------------------------------
__global__ __launch_bounds__(512) void eatab_kernel(
    const float* __restrict__ qa_embed_w,
    const float* __restrict__ erase_W,
    const float* __restrict__ erase_b,
    const float* __restrict__ add_W,
    const float* __restrict__ add_b,
    float*       __restrict__ eatab)
{
    __shared__ float4 qa4[16][32];

    const int tid = threadIdx.x;
    const int r0  = blockIdx.x * 16;

    {
        int row = tid >> 5, k4 = tid & 31;
        int r   = r0 + row; if (r > NQA_) r = NQA_;
        qa4[row][k4] = *reinterpret_cast<const float4*>(
            &qa_embed_w[(size_t)r * QD_ + k4 * 4]);
    }
    __syncthreads();

    const int  c   = tid & 255;
    const bool isE = tid < 256;
    const float* Wp = isE ? erase_W : add_W;

    float acc[16];
    #pragma unroll
    for (int r = 0; r < 16; ++r) acc[r] = 0.f;

    for (int k4 = 0; k4 < 32; ++k4) {
        float w0 = Wp[(size_t)(k4 * 4 + 0) * 256 + c];
        float w1 = Wp[(size_t)(k4 * 4 + 1) * 256 + c];
        float w2 = Wp[(size_t)(k4 * 4 + 2) * 256 + c];
        float w3 = Wp[(size_t)(k4 * 4 + 3) * 256 + c];
        #pragma unroll
        for (int r = 0; r < 16; ++r) {
            float4 qv = qa4[r][k4];
            acc[r] = fmaf(qv.x, w0, acc[r]);
            acc[r] = fmaf(qv.y, w1, acc[r]);
            acc[r] = fmaf(qv.z, w2, acc[r]);
            acc[r] = fmaf(qv.w, w3, acc[r]);
        }
    }

    const float bias = isE ? erase_b[c] : add_b[c];
    #pragma unroll
    for (int r = 0; r < 16; ++r) {
        float x = acc[r] + bias;
        float y;
        if (isE) {
            y = 1.f / (1.f + __expf(-x));
        } else {
            float t  = __expf(-2.f * fabsf(x));
            float ta = (1.f - t) / (1.f + t);
            y = (x < 0.f) ? -ta : ta;
        }
        if (r0 + r < EAROWS)
            eatab[(size_t)(r0 + r) * 512 + c * 2 + (isE ? 0 : 1)] = y;
    }
}

// ---------------------------------------------------------------------------
// Scan: 256 blocks (1/batch) x 1024 threads (16 waves/CU = 4/SIMD).
// Thread owns col = tid>>2, m-quarter mo = (tid&3)*16 -> mv[16] VGPR state.
// All data register-prefetched (no main-loop barriers, no LDS staging):
//  - w(t+1): 4x global_load_dwordx4, DIVERGENT addr (ms in it) so the
//    compiler cannot demote to SMEM; parity double-buffer wA/wB.
//  - (e,a)(t+2): one dwordx2 from interleaved eatab, parity slots.
//  - q/qa chains from LDS (broadcast ds_read_b32, 3-4 step lead).
// Reduction: 2 quad-local DPP adds; store by ms==0 lanes.
// ---------------------------------------------------------------------------
__global__ __launch_bounds__(1024, 1) void scan_kernel(
    const int*   __restrict__ q_data,
    const int*   __restrict__ qa_data,
    const float* __restrict__ init_mv,
    const float* __restrict__ wtab,
    const float* __restrict__ eatab,
    float*       __restrict__ out)
{
    __shared__ int qrow[S_];
    __shared__ int qarow[S_];

    const int b   = blockIdx.x;
    const int tid = threadIdx.x;
    const int col = tid >> 2;
    const int ms  = tid & 3;
    const int mo  = ms * 16;

    for (int i = tid; i < S_; i += 1024) {
        qrow[i]  = q_data[b * S_ + i];
        qarow[i] = qa_data[b * S_ + i];
    }
    __syncthreads();

    // quarter-column state: slot mo+k, column col
    float mv[16];
    #pragma unroll
    for (int k = 0; k < 16; ++k) mv[k] = init_mv[(mo + k) * VD_ + col];
    if (ms == 0) out[(size_t)b * S_ * VD_ + col] = 0.f;

    // index chains
    int qc  = qrow[0];
    int qn  = qrow[1];
    int qnn = qrow[2];
    int qa2 = qarow[2];
    int qa3 = qarow[3];

    // prime: w(q[0]) -> wA ; (e,a)(qa[0]) -> A ; (e,a)(qa[1]) -> B
    float4 wA[4], wB[4];
    {
        const float4* wrp = (const float4*)(wtab + (size_t)qrow[0] * 64 + mo);
        wA[0] = wrp[0]; wA[1] = wrp[1]; wA[2] = wrp[2]; wA[3] = wrp[3];
    }
    float2 eaA = *(const float2*)&eatab[(size_t)qarow[0] * 512 + col * 2];
    float2 eaB = *(const float2*)&eatab[(size_t)qarow[1] * 512 + col * 2];

    float* outp = &out[((size_t)b * S_ + 1) * VD_ + col];

    #define SCAN_STEP(WC, WL, EA, scur)                                        \
    {                                                                          \
        /* issue next step's w loads (divergent addr -> VMEM) */               \
        const float4* wrp = (const float4*)(wtab + (size_t)qn * 64 + mo);      \
        WL[0] = wrp[0]; WL[1] = wrp[1]; WL[2] = wrp[2]; WL[3] = wrp[3];        \
        const bool  wg = qc >= 1;                                              \
        const float em = wg ? EA.x : 0.f;                                      \
        const float am = wg ? EA.y : 0.f;                                      \
        /* reload this parity's (e,a) slot for step scur+2 */                  \
        EA = *(const float2*)&eatab[(size_t)qa2 * 512 + col * 2];              \
        /* rotate chains: fetch q[scur+3], qa[scur+4] */                       \
        int t3 = (scur) + 3; if (t3 >= S_) t3 = S_ - 1;                        \
        int t4 = (scur) + 4; if (t4 >= S_) t4 = S_ - 1;                        \
        const int qnew  = qrow[t3];                                            \
        const int qanew = qarow[t4];                                           \
        qc = qn; qn = qnn; qnn = qnew;                                         \
        qa2 = qa3; qa3 = qanew;                                                \
        float r0 = 0.f, r1 = 0.f, r2 = 0.f, r3 = 0.f;                          \
        _Pragma("unroll")                                                      \
        for (int k = 0; k < 4; ++k) {                                          \
            const float4 w4 = WC[k];                                           \
            const float v0 = mv[4 * k + 0];                                    \
            const float v1 = mv[4 * k + 1];                                    \
            const float v2 = mv[4 * k + 2];                                    \
            const float v3 = mv[4 * k + 3];                                    \
            r0 = fmaf(w4.x, v0, r0);                                           \
            r1 = fmaf(w4.y, v1, r1);                                           \
            r2 = fmaf(w4.z, v2, r2);                                           \
            r3 = fmaf(w4.w, v3, r3);                                           \
            mv[4 * k + 0] = fmaf(w4.x, fmaf(-em, v0, am), v0);                 \
            mv[4 * k + 1] = fmaf(w4.y, fmaf(-em, v1, am), v1);                 \
            mv[4 * k + 2] = fmaf(w4.z, fmaf(-em, v2, am), v2);                 \
            mv[4 * k + 3] = fmaf(w4.w, fmaf(-em, v3, am), v3);                 \
        }                                                                      \
        float rd = qadd2(qadd1((r0 + r1) + (r2 + r3)));                        \
        if (ms == 0 && (scur) + 1 < S_)                                        \
            outp[0] = rd;                                                      \
        outp += VD_;                                                           \
    }

    for (int t = 0; t < S_; t += 2) {
        SCAN_STEP(wA, wB, eaA, t)
        SCAN_STEP(wB, wA, eaB, t + 1)
    }
    #undef SCAN_STEP
}

// ---------------------------------------------------------------------------
extern "C" void kernel_launch(void* const* d_in, const int* in_sizes, int n_in,
                              void* d_out, int out_size, void* d_ws, size_t ws_size,
                              hipStream_t stream)
{
    const int*   q_data  = (const int*)  d_in[0];
    const int*   qa_data = (const int*)  d_in[1];
    const float* q_emb   = (const float*)d_in[2];
    const float* qa_emb  = (const float*)d_in[3];
    const float* key_mem = (const float*)d_in[4];
    const float* init_mv = (const float*)d_in[5];
    const float* erase_W = (const float*)d_in[6];
    const float* erase_b = (const float*)d_in[7];
    const float* add_W   = (const float*)d_in[8];
    const float* add_b   = (const float*)d_in[9];
    float* out = (float*)d_out;

    char* ws = (char*)d_ws;
    float4* kTq = (float4*)ws;
    size_t off = (size_t)2048 * sizeof(float4);               // 32 KB
    float* wtab = (float*)(ws + off);
    off += (size_t)WROWS * 64 * sizeof(float);                // 2.56 MB
    off = (off + 255) & ~(size_t)255;
    float* eatab = (float*)(ws + off);
    off += (size_t)EAROWS * 512 * sizeof(float);              // 40.96 MB

    kT_kernel<<<dim3(8), dim3(256), 0, stream>>>(key_mem, kTq);
    wtab_kernel<<<dim3((WROWS + 15) / 16), dim3(256), 0, stream>>>(
        q_emb, kTq, wtab);
    eatab_kernel<<<dim3((EAROWS + 15) / 16), dim3(512), 0, stream>>>(
        qa_emb, erase_W, erase_b, add_W, add_b, eatab);
    scan_kernel<<<dim3(B_), dim3(1024), 0, stream>>>(
        q_data, qa_data, init_mv, wtab, eatab, out);
}

// Round 12
// 320.994 us; speedup vs baseline: 1.9434x; 1.9434x over previous
//
#include <hip/hip_runtime.h>
#include <math.h>

#define B_     256
#define S_     500
#define QD_    128
#define M_     64
#define VD_    256
#define CH_    16
#define NQ_    10000          // q indices in [0, 10000]
#define NQA_   20000          // qa indices in [0, 20000]
#define WROWS  (NQ_ + 1)
#define EAROWS (NQA_ + 1)

typedef unsigned int u32;

// global -> LDS async copy, 16B per lane. LDS dest = wave-uniform base + lane*16.
__device__ __forceinline__ void gload_lds16(const float* g, float* l)
{
    __builtin_amdgcn_global_load_lds(
        (const __attribute__((address_space(1))) u32*)(const void*)g,
        (__attribute__((address_space(3))) u32*)(void*)l, 16, 0, 0);
}

// lane-local partial-sum combines via DPP (pure VALU):
// qadd1: x += x[lane^1]; qadd2: x += x[lane^2]; qaddm: x += x[7-(lane&7) half-mirror]
__device__ __forceinline__ float qadd1(float x)
{
    int r = __builtin_amdgcn_mov_dpp(__float_as_int(x), 0xB1, 0xF, 0xF, true);
    return x + __int_as_float(r);
}
__device__ __forceinline__ float qadd2(float x)
{
    int r = __builtin_amdgcn_mov_dpp(__float_as_int(x), 0x4E, 0xF, 0xF, true);
    return x + __int_as_float(r);
}
__device__ __forceinline__ float qaddm(float x)
{
    int r = __builtin_amdgcn_mov_dpp(__float_as_int(x), 0x141, 0xF, 0xF, true);
    return x + __int_as_float(r);
}

// ---------------------------------------------------------------------------
// Transpose key_mem [64][128] into quad layout kTq[k4*64 + m].
// ---------------------------------------------------------------------------
__global__ void kT_kernel(const float* __restrict__ key_mem, float4* __restrict__ kTq)
{
    int i = blockIdx.x * 256 + threadIdx.x;
    if (i < 32 * 64) {
        int m  = i & 63;
        int k4 = i >> 6;
        kTq[i] = *reinterpret_cast<const float4*>(&key_mem[m * QD_ + k4 * 4]);
    }
}

// ---------------------------------------------------------------------------
// wtab[r][m] = softmax_m( q_embed_w[r] . key_mem[m] ),  r in [0, WROWS)
// ---------------------------------------------------------------------------
__global__ __launch_bounds__(256) void wtab_kernel(
    const float*  __restrict__ q_embed_w,
    const float4* __restrict__ kTq,
    float*        __restrict__ wtab)
{
    __shared__ float4 q4[16][32];

    const int tid = threadIdx.x;
    const int r0  = blockIdx.x * 16;

    for (int i = tid; i < 512; i += 256) {
        int row = i >> 5, k4 = i & 31;
        int r   = r0 + row; if (r > NQ_) r = NQ_;
        q4[row][k4] = *reinterpret_cast<const float4*>(
            &q_embed_w[(size_t)r * QD_ + k4 * 4]);
    }
    __syncthreads();

    const int wave = tid >> 6, lane = tid & 63;
    const int rr = wave * 4;

    float s0 = 0.f, s1 = 0.f, s2 = 0.f, s3 = 0.f;
    for (int k4 = 0; k4 < 32; ++k4) {
        float4 kv = kTq[k4 * 64 + lane];
        float4 a0 = q4[rr + 0][k4];
        float4 a1 = q4[rr + 1][k4];
        float4 a2 = q4[rr + 2][k4];
        float4 a3 = q4[rr + 3][k4];
        s0 = fmaf(a0.x, kv.x, s0); s0 = fmaf(a0.y, kv.y, s0);
        s0 = fmaf(a0.z, kv.z, s0); s0 = fmaf(a0.w, kv.w, s0);
        s1 = fmaf(a1.x, kv.x, s1); s1 = fmaf(a1.y, kv.y, s1);
        s1 = fmaf(a1.z, kv.z, s1); s1 = fmaf(a1.w, kv.w, s1);
        s2 = fmaf(a2.x, kv.x, s2); s2 = fmaf(a2.y, kv.y, s2);
        s2 = fmaf(a2.z, kv.z, s2); s2 = fmaf(a2.w, kv.w, s2);
        s3 = fmaf(a3.x, kv.x, s3); s3 = fmaf(a3.y, kv.y, s3);
        s3 = fmaf(a3.z, kv.z, s3); s3 = fmaf(a3.w, kv.w, s3);
    }

    float s[4] = { s0, s1, s2, s3 };
    #pragma unroll
    for (int j = 0; j < 4; ++j) {
        float mx = s[j];
        #pragma unroll
        for (int off = 32; off; off >>= 1) mx = fmaxf(mx, __shfl_xor(mx, off));
        float e = __expf(s[j] - mx);
        float sum = e;
        #pragma unroll
        for (int off = 32; off; off >>= 1) sum += __shfl_xor(sum, off);
        if (r0 + rr + j < WROWS)
            wtab[(size_t)(r0 + rr + j) * 64 + lane] = e / sum;
    }
}

// ---------------------------------------------------------------------------
// eatab INTERLEAVED: eatab[r][c*2+0] = sigmoid(...), [c*2+1] = tanh(...)
// ---------------------------------------------------------------------------
__global__ __launch_bounds__(512) void eatab_kernel(
    const float* __restrict__ qa_embed_w,
    const float* __restrict__ erase_W,
    const float* __restrict__ erase_b,
    const float* __restrict__ add_W,
    const float* __restrict__ add_b,
    float*       __restrict__ eatab)
{
    __shared__ float4 qa4[16][32];

    const int tid = threadIdx.x;
    const int r0  = blockIdx.x * 16;

    {
        int row = tid >> 5, k4 = tid & 31;
        int r   = r0 + row; if (r > NQA_) r = NQA_;
        qa4[row][k4] = *reinterpret_cast<const float4*>(
            &qa_embed_w[(size_t)r * QD_ + k4 * 4]);
    }
    __syncthreads();

    const int  c   = tid & 255;
    const bool isE = tid < 256;
    const float* Wp = isE ? erase_W : add_W;

    float acc[16];
    #pragma unroll
    for (int r = 0; r < 16; ++r) acc[r] = 0.f;

    for (int k4 = 0; k4 < 32; ++k4) {
        float w0 = Wp[(size_t)(k4 * 4 + 0) * 256 + c];
        float w1 = Wp[(size_t)(k4 * 4 + 1) * 256 + c];
        float w2 = Wp[(size_t)(k4 * 4 + 2) * 256 + c];
        float w3 = Wp[(size_t)(k4 * 4 + 3) * 256 + c];
        #pragma unroll
        for (int r = 0; r < 16; ++r) {
            float4 qv = qa4[r][k4];
            acc[r] = fmaf(qv.x, w0, acc[r]);
            acc[r] = fmaf(qv.y, w1, acc[r]);
            acc[r] = fmaf(qv.z, w2, acc[r]);
            acc[r] = fmaf(qv.w, w3, acc[r]);
        }
    }

    const float bias = isE ? erase_b[c] : add_b[c];
    #pragma unroll
    for (int r = 0; r < 16; ++r) {
        float x = acc[r] + bias;
        float y;
        if (isE) {
            y = 1.f / (1.f + __expf(-x));
        } else {
            float t  = __expf(-2.f * fabsf(x));
            float ta = (1.f - t) / (1.f + t);
            y = (x < 0.f) ? -ta : ta;
        }
        if (r0 + r < EAROWS)
            eatab[(size_t)(r0 + r) * 512 + c * 2 + (isE ? 0 : 1)] = y;
    }
}

// ---------------------------------------------------------------------------
// Scan staging: w rows (all 64 m) + interleaved e/a for THIS BLOCK's 128
// columns, one CH_-step chunk, via global_load_lds.
//   wbuf[st*64 + m] ; eabuf[st*256 + cl*2(+0 e / +1 a)], cl = local col
// ---------------------------------------------------------------------------
__device__ __forceinline__ void stage_chunk(
    int tb, int tid, int cb,
    const int* __restrict__ qrow, const int* __restrict__ qarow,
    const float* __restrict__ wtab, const float* __restrict__ eatab,
    float* wbuf, float* eabuf)
{
    if (tid < 256) {
        int st = tb + (tid >> 4); if (st >= S_) st = S_ - 1;
        gload_lds16(&wtab[(size_t)qrow[st] * 64 + (tid & 15) * 4],
                    &wbuf[(tid & ~63) * 4]);
    }
    #pragma unroll
    for (int j = 0; j < 2; ++j) {
        const int idx = tid + 512 * j;          // 0..1023 quads
        int st = tb + (idx >> 6); if (st >= S_) st = S_ - 1;
        const int cq = (idx & 63) * 4;
        gload_lds16(&eatab[(size_t)qarow[st] * 512 + cb * 256 + cq],
                    &eabuf[(idx & ~63) * 4]);
    }
}

// ---------------------------------------------------------------------------
// Scan: grid = B_*2 (block owns batch b = bid>>1, column half cb = bid&1),
// 512 threads, __launch_bounds__(512,4) -> 2 blocks/CU = 16 waves/CU.
// Thread: mgrp = tid&7 owns m-slots [mgrp*8, mgrp*8+8); colg = tid>>3 owns
// local cols 2*colg, 2*colg+1 -> mv0[8]/mv1[8] VGPR state.
// Per step: 2 ds_read_b128 (w) + 1 ds_read_b128 (e/a pair) + 48 FMA +
// 6 DPP-adds (xor1, xor2, half-mirror over the 8 mgrp lanes) + float2 store.
// A/B software pipeline inside fully-unrolled chunks; gload_lds staging
// behind __syncthreads (the compiler-proof prefetch structure).
// ---------------------------------------------------------------------------
__global__ __launch_bounds__(512, 4) void scan_kernel(
    const int*   __restrict__ q_data,
    const int*   __restrict__ qa_data,
    const float* __restrict__ init_mv,
    const float* __restrict__ wtab,
    const float* __restrict__ eatab,
    float*       __restrict__ out)
{
    __shared__ float w_lds[2][CH_ * 64];      // 8 KB
    __shared__ float ea_lds[2][CH_ * 256];    // 32 KB
    __shared__ int   qrow[S_];
    __shared__ int   qarow[S_];

    const int bid  = blockIdx.x;
    const int b    = bid >> 1;
    const int cb   = bid & 1;
    const int tid  = threadIdx.x;
    const int mgrp = tid & 7;
    const int colg = tid >> 3;               // 0..63
    const int mo   = mgrp * 8;
    const int col  = cb * 128 + colg * 2;    // global cols col, col+1

    for (int i = tid; i < S_; i += 512) {
        qrow[i]  = q_data[b * S_ + i];
        qarow[i] = qa_data[b * S_ + i];
    }
    __syncthreads();                          // indices ready for staging

    stage_chunk(0, tid, cb, qrow, qarow, wtab, eatab, w_lds[0], ea_lds[0]);

    // state: slot mo+k, columns col (mv0) and col+1 (mv1)
    float mv0[8], mv1[8];
    #pragma unroll
    for (int k = 0; k < 8; ++k) {
        float2 iv = *reinterpret_cast<const float2*>(&init_mv[(mo + k) * VD_ + col]);
        mv0[k] = iv.x;
        mv1[k] = iv.y;
    }
    if (mgrp == 0)
        *reinterpret_cast<float2*>(&out[(size_t)b * S_ * VD_ + col]) = make_float2(0.f, 0.f);

    __syncthreads();                          // chunk 0 staged (vmcnt drained)

    const int nch = (S_ + CH_ - 1) / CH_;
    for (int c = 0; c < nch; ++c) {
        const int  tb   = c * CH_;
        const int  full = (S_ - tb >= CH_);
        const int  buf  = c & 1;
        const bool hn   = (c + 1 < nch);

        if (hn)
            stage_chunk(tb + CH_, tid, cb, qrow, qarow, wtab, eatab,
                        w_lds[buf ^ 1], ea_lds[buf ^ 1]);

        const float* wb = &w_lds[buf][mo];
        const float* eb = &ea_lds[buf][colg * 4];
        float* outp = &out[((size_t)b * S_ + tb + 1) * VD_ + col];

        float4 wq0A, wq1A, wq0B, wq1B, eaA, eaB;
        int    qrA, qrB;

        #define LOADS(tt, SS)                                                   \
            wq0##SS = *reinterpret_cast<const float4*>(wb + (tt) * 64);         \
            wq1##SS = *reinterpret_cast<const float4*>(wb + (tt) * 64 + 4);     \
            ea##SS  = *reinterpret_cast<const float4*>(eb + (tt) * 256);        \
            qr##SS  = qrow[tb + (tt)];

        #define QE(W, K) {                                                      \
            const float v0 = mv0[K], v1 = mv1[K];                               \
            r0 = fmaf(W, v0, r0);                                               \
            r1 = fmaf(W, v1, r1);                                               \
            mv0[K] = fmaf(W, fmaf(-em0, v0, am0), v0);                          \
            mv1[K] = fmaf(W, fmaf(-em1, v1, am1), v1);                          \
        }

        #define COMP(tt, SS, GUARD) {                                           \
            const bool  wr  = qr##SS >= 1;                                      \
            const float em0 = wr ? ea##SS.x : 0.f;                              \
            const float am0 = wr ? ea##SS.y : 0.f;                              \
            const float em1 = wr ? ea##SS.z : 0.f;                              \
            const float am1 = wr ? ea##SS.w : 0.f;                              \
            float r0 = 0.f, r1 = 0.f;                                           \
            QE(wq0##SS.x, 0) QE(wq0##SS.y, 1) QE(wq0##SS.z, 2) QE(wq0##SS.w, 3) \
            QE(wq1##SS.x, 4) QE(wq1##SS.y, 5) QE(wq1##SS.z, 6) QE(wq1##SS.w, 7) \
            float rd0 = qaddm(qadd2(qadd1(r0)));                                \
            float rd1 = qaddm(qadd2(qadd1(r1)));                                \
            if (mgrp == 0 && (GUARD))                                           \
                *reinterpret_cast<float2*>(&outp[(size_t)(tt) * VD_]) =         \
                    make_float2(rd0, rd1);                                      \
        }

        if (full) {
            LOADS(0, A)
            LOADS(1,  B) COMP(0,  A, true)
            LOADS(2,  A) COMP(1,  B, true)
            LOADS(3,  B) COMP(2,  A, true)
            LOADS(4,  A) COMP(3,  B, true)
            LOADS(5,  B) COMP(4,  A, true)
            LOADS(6,  A) COMP(5,  B, true)
            LOADS(7,  B) COMP(6,  A, true)
            LOADS(8,  A) COMP(7,  B, true)
            LOADS(9,  B) COMP(8,  A, true)
            LOADS(10, A) COMP(9,  B, true)
            LOADS(11, B) COMP(10, A, true)
            LOADS(12, A) COMP(11, B, true)
            LOADS(13, B) COMP(12, A, true)
            LOADS(14, A) COMP(13, B, true)
            LOADS(15, B) COMP(14, A, true)
            COMP(15, B, true)
        } else {
            #define TSTEP(tt)                                                   \
            if (tb + (tt) < S_) {                                               \
                LOADS(tt, A)                                                    \
                COMP(tt, A, tb + (tt) + 1 < S_)                                 \
            }
            TSTEP(0)  TSTEP(1)  TSTEP(2)  TSTEP(3)
            TSTEP(4)  TSTEP(5)  TSTEP(6)  TSTEP(7)
            TSTEP(8)  TSTEP(9)  TSTEP(10) TSTEP(11)
            TSTEP(12) TSTEP(13) TSTEP(14) TSTEP(15)
            #undef TSTEP
        }

        #undef COMP
        #undef QE
        #undef LOADS

        __syncthreads();   // next chunk staged + everyone done with buf
    }
}

// ---------------------------------------------------------------------------
extern "C" void kernel_launch(void* const* d_in, const int* in_sizes, int n_in,
                              void* d_out, int out_size, void* d_ws, size_t ws_size,
                              hipStream_t stream)
{
    const int*   q_data  = (const int*)  d_in[0];
    const int*   qa_data = (const int*)  d_in[1];
    const float* q_emb   = (const float*)d_in[2];
    const float* qa_emb  = (const float*)d_in[3];
    const float* key_mem = (const float*)d_in[4];
    const float* init_mv = (const float*)d_in[5];
    const float* erase_W = (const float*)d_in[6];
    const float* erase_b = (const float*)d_in[7];
    const float* add_W   = (const float*)d_in[8];
    const float* add_b   = (const float*)d_in[9];
    float* out = (float*)d_out;

    char* ws = (char*)d_ws;
    float4* kTq = (float4*)ws;
    size_t off = (size_t)2048 * sizeof(float4);               // 32 KB
    float* wtab = (float*)(ws + off);
    off += (size_t)WROWS * 64 * sizeof(float);                // 2.56 MB
    off = (off + 255) & ~(size_t)255;
    float* eatab = (float*)(ws + off);
    off += (size_t)EAROWS * 512 * sizeof(float);              // 40.96 MB

    kT_kernel<<<dim3(8), dim3(256), 0, stream>>>(key_mem, kTq);
    wtab_kernel<<<dim3((WROWS + 15) / 16), dim3(256), 0, stream>>>(
        q_emb, kTq, wtab);
    eatab_kernel<<<dim3((EAROWS + 15) / 16), dim3(512), 0, stream>>>(
        qa_emb, erase_W, erase_b, add_W, add_b, eatab);
    scan_kernel<<<dim3(B_ * 2), dim3(512), 0, stream>>>(
        q_data, qa_data, init_mv, wtab, eatab, out);
}